// Round 4
// baseline (261.907 us; speedup 1.0000x reference)
//
#include <hip/hip_runtime.h>
#include <cstdint>
#include <cstddef>

typedef __attribute__((ext_vector_type(8))) short bf16x8;
typedef __attribute__((ext_vector_type(4))) float f32x4;
typedef __attribute__((ext_vector_type(4))) unsigned short u16x4;

#define AS1 __attribute__((address_space(1)))
#define AS3 __attribute__((address_space(3)))

__device__ __forceinline__ unsigned short f2bf(float f) {
  union { float f; unsigned int u; } v; v.f = f;
  unsigned int r = v.u + 0x7fffu + ((v.u >> 16) & 1u);
  return (unsigned short)(r >> 16);
}

__device__ __forceinline__ void gll16(const unsigned short* g, unsigned short* l) {
  __builtin_amdgcn_global_load_lds((const AS1 void*)g, (AS3 void*)l, 16, 0, 0);
}

// ---------------- x convert ----------------
__global__ __launch_bounds__(256) void cvt_bf16_kernel(const float* __restrict__ src,
                                                       unsigned short* __restrict__ dst, int n) {
  int idx = (blockIdx.x * blockDim.x + threadIdx.x) * 4;
  if (idx >= n) return;
  const float* s = src + idx;
  u16x4 o = { f2bf(s[0]), f2bf(s[1]), f2bf(s[2]), f2bf(s[3]) };
  *(u16x4*)(dst + idx) = o;
}

// ---------------- ALL weight transposes in one dispatch ----------------
// z 0..7:  Wg[e]  1024x512  -> WguT[e] even rows (drp 2048)
// z 8..15: Wu[e]  1024x512  -> WguT[e] odd rows
// z 16..23:Wd[e]  512x1024  -> WdT[e]  (drp 512)
// z 24: Sg -> SguT even; z 25: Su -> SguT odd; z 26: Sd -> SdT
__global__ __launch_bounds__(256) void transpose_cvt_all(
    const float* __restrict__ Wg, const float* __restrict__ Wu,
    const float* __restrict__ Wd, const float* __restrict__ Sg,
    const float* __restrict__ Su, const float* __restrict__ Sd,
    unsigned short* __restrict__ WguT, unsigned short* __restrict__ WdT,
    unsigned short* __restrict__ SguT, unsigned short* __restrict__ SdT) {
  const int z = blockIdx.z;
  const float* src; unsigned short* dst; int R, C, drp;
  if (z < 8)       { src = Wg + (size_t)z * 524288; dst = WguT + (size_t)z * 1048576; R = 1024; C = 512; drp = 2048; }
  else if (z < 16) { src = Wu + (size_t)(z - 8) * 524288; dst = WguT + (size_t)(z - 8) * 1048576 + 1024; R = 1024; C = 512; drp = 2048; }
  else if (z < 24) { src = Wd + (size_t)(z - 16) * 524288; dst = WdT + (size_t)(z - 16) * 524288; R = 512; C = 1024; drp = 512; }
  else if (z == 24){ src = Sg; dst = SguT; R = 1024; C = 1024; drp = 2048; }
  else if (z == 25){ src = Su; dst = SguT + 1024; R = 1024; C = 1024; drp = 2048; }
  else             { src = Sd; dst = SdT; R = 1024; C = 1024; drp = 1024; }
  const int c0 = blockIdx.x * 64, r0 = blockIdx.y * 64;
  if (c0 >= C || r0 >= R) return;
  __shared__ float tile[64][65];
  const int tc = threadIdx.x & 63, tr = threadIdx.x >> 6;
#pragma unroll
  for (int i = 0; i < 16; i++) {
    int r = tr + i * 4;
    tile[r][tc] = src[(size_t)(r0 + r) * C + c0 + tc];
  }
  __syncthreads();
#pragma unroll
  for (int i = 0; i < 16; i++) {
    int cc = tr + i * 4;
    dst[(size_t)(c0 + cc) * drp + (r0 + tc)] = f2bf(tile[tc][cc]);
  }
}

// ---------------- router: logits ----------------
__global__ __launch_bounds__(256) void logits_kernel(const float* __restrict__ x,
                                                     const float* __restrict__ Wr,
                                                     float* __restrict__ logits) {
  const int t = blockIdx.x * 4 + (threadIdx.x >> 6);
  const int lane = threadIdx.x & 63;
  const float* xr = x + (size_t)t * 1024;
  float acc[8];
#pragma unroll
  for (int e = 0; e < 8; e++) acc[e] = 0.f;
#pragma unroll
  for (int i = 0; i < 16; i++) {
    int d = lane + i * 64;
    float xv = xr[d];
    const float4* w = (const float4*)(Wr + d * 8);
    float4 w0 = w[0], w1 = w[1];
    acc[0] += xv * w0.x; acc[1] += xv * w0.y; acc[2] += xv * w0.z; acc[3] += xv * w0.w;
    acc[4] += xv * w1.x; acc[5] += xv * w1.y; acc[6] += xv * w1.z; acc[7] += xv * w1.w;
  }
#pragma unroll
  for (int off = 32; off > 0; off >>= 1)
#pragma unroll
    for (int e = 0; e < 8; e++) acc[e] += __shfl_down(acc[e], off);
  if (lane == 0) {
#pragma unroll
    for (int e = 0; e < 8; e++) logits[t * 8 + e] = acc[e];
  }
}

// ---------------- router: assignment (single block, LDS atomics) ----------------
__global__ __launch_bounds__(1024) void assign_kernel(
    const float* __restrict__ logits, const float* __restrict__ bias,
    int* __restrict__ list, int* __restrict__ ridx, float* __restrict__ rp,
    int* __restrict__ counts_g, int* __restrict__ offs_g) {
  __shared__ int cnt[8];
  __shared__ int offs[9];
  const int tid = threadIdx.x;
  if (tid < 8) cnt[tid] = 0;
  __syncthreads();
  int te[2][2], tpos[2][2];
  float tp[2][2];
#pragma unroll
  for (int it = 0; it < 2; it++) {
    int t = tid + it * 1024;
    float v[8];
#pragma unroll
    for (int e = 0; e < 8; e++) v[e] = logits[t * 8 + e] + bias[e];
    int i0 = 0;
#pragma unroll
    for (int e = 1; e < 8; e++) if (v[e] > v[i0]) i0 = e;
    int i1 = (i0 == 0) ? 1 : 0;
#pragma unroll
    for (int e = 0; e < 8; e++) if (e != i0 && v[e] > v[i1]) i1 = e;
    float pa = 1.f / (1.f + __expf(v[i1] - v[i0]));
    te[it][0] = i0; te[it][1] = i1;
    tp[it][0] = pa; tp[it][1] = 1.f - pa;
    tpos[it][0] = atomicAdd(&cnt[i0], 1);
    tpos[it][1] = atomicAdd(&cnt[i1], 1);
  }
  __syncthreads();
  if (tid == 0) {
    int s = 0;
#pragma unroll
    for (int e = 0; e < 8; e++) { offs[e] = s; s += cnt[e]; }
    offs[8] = s;
#pragma unroll
    for (int e = 0; e < 8; e++) { counts_g[e] = cnt[e]; offs_g[e] = offs[e]; }
    offs_g[8] = s;
  }
  __syncthreads();
#pragma unroll
  for (int it = 0; it < 2; it++) {
    int t = tid + it * 1024;
#pragma unroll
    for (int k = 0; k < 2; k++) {
      int grow = offs[te[it][k]] + tpos[it][k];
      list[grow] = t;
      ridx[t * 2 + k] = grow;
      rp[t * 2 + k] = tp[it][k];
    }
  }
}

// ---------------- fused TN GEMM, 64x128 tile ----------------
// MODE 0: gate|up. z<8: A=Xb gathered, B=WguT[e], H=He+offs[e]*512. z==8: shared.
// MODE 1: down.   z<8: A=He+offs[e]*512 (K=512), B=WdT[e], D=De+offs[e]*1024. z==8: shared.
template <int MODE>
__global__ __launch_bounds__(256, 4) void gemm_tn_kernel(
    const unsigned short* __restrict__ Xb, const unsigned short* __restrict__ He,
    const unsigned short* __restrict__ Hs, const unsigned short* __restrict__ Wgu,
    const unsigned short* __restrict__ Sgu, const unsigned short* __restrict__ Wd,
    const unsigned short* __restrict__ Sd, unsigned short* __restrict__ HeOut,
    unsigned short* __restrict__ HsOut, float* __restrict__ De, float* __restrict__ Ds,
    const int* __restrict__ list, const int* __restrict__ counts,
    const int* __restrict__ offs) {
  const int ez = blockIdx.z;
  int cnt, lda, K;
  const unsigned short* A;
  const unsigned short* B;
  const int* alist = nullptr;
  unsigned short* H = nullptr;
  float* D = nullptr;
  int ldh = 0;

  if (MODE == 0) {
    if (ez < 8) {
      if (blockIdx.y >= 8) return;
      cnt = counts[ez]; A = Xb; alist = list + offs[ez]; lda = 1024; K = 1024;
      B = Wgu + (size_t)ez * 1024 * 1024; H = HeOut + (size_t)offs[ez] * 512; ldh = 512;
    } else {
      cnt = 2048; A = Xb; lda = 1024; K = 1024; B = Sgu; H = HsOut; ldh = 1024;
    }
  } else {
    if (ez < 8) {
      if (blockIdx.y >= 8) return;
      cnt = counts[ez]; A = He + (size_t)offs[ez] * 512; lda = 512; K = 512;
      B = Wd + (size_t)ez * 1024 * 512; D = De + (size_t)offs[ez] * 1024;
    } else {
      cnt = 2048; A = Hs; lda = 1024; K = 1024; B = Sd; D = Ds;
    }
  }

  const int m0 = blockIdx.x * 64;
  if (m0 >= cnt) return;
  const int n0 = blockIdx.y * 128;

  __shared__ unsigned short As[64 * 32];    // 4 KB
  __shared__ unsigned short Bs[128 * 32];   // 8 KB

  const int tid = threadIdx.x;
  const int srow = tid >> 2;
  const int scol = (tid & 3) * 8;
  const int wuni = (tid >> 6) * 512;

  int r0 = m0 + srow; if (r0 >= cnt) r0 = cnt - 1;
  size_t abase;
  if (MODE == 0 && ez < 8) abase = (size_t)alist[r0] * lda;
  else abase = (size_t)r0 * lda;
  const size_t bbase0 = (size_t)(n0 + srow) * K;
  const size_t bbase1 = (size_t)(n0 + srow + 64) * K;

  const int wave = tid >> 6;
  const int lane = tid & 63;
  const int wn = wave * 32;
  const int fl = lane & 15;
  const int q = lane >> 4;

  f32x4 acc[4][2];
  f32x4 zero = {0.f, 0.f, 0.f, 0.f};
#pragma unroll
  for (int i = 0; i < 4; i++)
#pragma unroll
    for (int j = 0; j < 2; j++) acc[i][j] = zero;

  for (int k0 = 0; k0 < K; k0 += 32) {
    __syncthreads();
    gll16(A + abase + k0 + scol, &As[wuni]);
    gll16(B + bbase0 + k0 + scol, &Bs[wuni]);
    gll16(B + bbase1 + k0 + scol, &Bs[2048 + wuni]);
    __syncthreads();

    bf16x8 af[4], bfr[2];
#pragma unroll
    for (int i = 0; i < 4; i++) af[i] = *(const bf16x8*)(&As[(i * 16 + fl) * 32 + q * 8]);
#pragma unroll
    for (int j = 0; j < 2; j++) bfr[j] = *(const bf16x8*)(&Bs[(wn + j * 16 + fl) * 32 + q * 8]);
#pragma unroll
    for (int i = 0; i < 4; i++)
#pragma unroll
      for (int j = 0; j < 2; j++)
        acc[i][j] = __builtin_amdgcn_mfma_f32_16x16x32_bf16(af[i], bfr[j], acc[i][j], 0, 0, 0);
  }

  if (MODE == 0) {
#pragma unroll
    for (int i = 0; i < 4; i++) {
#pragma unroll
      for (int j = 0; j < 2; j++) {
#pragma unroll
        for (int r = 0; r < 4; r++) {
          int grow = m0 + i * 16 + q * 4 + r;
          float v = acc[i][j][r];
          float pv = __shfl_xor(v, 1);
          if ((lane & 1) == 0 && grow < cnt) {
            float s = v / (1.f + __expf(-v));
            int colh = (n0 + wn + j * 16 + fl) >> 1;
            H[(size_t)grow * ldh + colh] = f2bf(s * pv);
          }
        }
      }
    }
  } else {
#pragma unroll
    for (int i = 0; i < 4; i++) {
#pragma unroll
      for (int r = 0; r < 4; r++) {
        int grow = m0 + i * 16 + q * 4 + r;
        if (grow >= cnt) continue;
#pragma unroll
        for (int j = 0; j < 2; j++) {
          int col = n0 + wn + j * 16 + fl;
          D[(size_t)grow * 1024 + col] = acc[i][j][r];
        }
      }
    }
  }
}

// ---------------- combine ----------------
__global__ __launch_bounds__(256) void combine_kernel(
    const float* __restrict__ Ds, const float* __restrict__ De,
    const int* __restrict__ ridx, const float* __restrict__ rp,
    float* __restrict__ out) {
  const int t = blockIdx.x;
  const int i0 = ridx[t * 2], i1 = ridx[t * 2 + 1];
  const float p0 = rp[t * 2], p1 = rp[t * 2 + 1];
  const float4* a  = (const float4*)(Ds + (size_t)t * 1024);
  const float4* b0 = (const float4*)(De + (size_t)i0 * 1024);
  const float4* b1 = (const float4*)(De + (size_t)i1 * 1024);
  float4* o = (float4*)(out + (size_t)t * 1024);
  int c = threadIdx.x;
  float4 va = a[c], v0 = b0[c], v1 = b1[c];
  float4 r;
  r.x = va.x + p0 * v0.x + p1 * v1.x;
  r.y = va.y + p0 * v0.y + p1 * v1.y;
  r.z = va.z + p0 * v0.z + p1 * v1.z;
  r.w = va.w + p0 * v0.w + p1 * v1.w;
  o[c] = r;
}

// ---------------- launch ----------------
extern "C" void kernel_launch(void* const* d_in, const int* in_sizes, int n_in,
                              void* d_out, int out_size, void* d_ws, size_t ws_size,
                              hipStream_t stream) {
  const float* x    = (const float*)d_in[0];
  const float* Wr   = (const float*)d_in[1];
  const float* Wg   = (const float*)d_in[2];
  const float* Wu   = (const float*)d_in[3];
  const float* Wd   = (const float*)d_in[4];
  const float* Sg   = (const float*)d_in[5];
  const float* Su   = (const float*)d_in[6];
  const float* Sd   = (const float*)d_in[7];
  const float* bias = (const float*)d_in[8];
  float* out = (float*)d_out;

  char* ws = (char*)d_ws;
  size_t o = 0;
  auto alloc = [&](size_t b) { char* p = ws + o; o += (b + 255) & ~(size_t)255; return p; };
  unsigned short* Xb   = (unsigned short*)alloc((size_t)2048 * 1024 * 2);
  unsigned short* WguT = (unsigned short*)alloc((size_t)8 * 1024 * 1024 * 2);
  unsigned short* WdT  = (unsigned short*)alloc((size_t)8 * 1024 * 512 * 2);
  unsigned short* SguT = (unsigned short*)alloc((size_t)2048 * 1024 * 2);
  unsigned short* SdT  = (unsigned short*)alloc((size_t)1024 * 1024 * 2);
  float* logits = (float*)alloc((size_t)2048 * 8 * 4);
  int*   list   = (int*)alloc((size_t)4096 * 4);
  int*   ridx   = (int*)alloc((size_t)2048 * 2 * 4);
  float* rp     = (float*)alloc((size_t)2048 * 2 * 4);
  int*   counts = (int*)alloc(64);
  int*   offs   = (int*)alloc(64);
  unsigned short* He = (unsigned short*)alloc((size_t)4096 * 512 * 2);
  unsigned short* Hs = (unsigned short*)alloc((size_t)2048 * 1024 * 2);
  float* De = (float*)alloc((size_t)4096 * 1024 * 4);
  float* Ds = (float*)alloc((size_t)2048 * 1024 * 4);

  cvt_bf16_kernel<<<2048, 256, 0, stream>>>(x, Xb, 2048 * 1024);
  transpose_cvt_all<<<dim3(16, 16, 27), 256, 0, stream>>>(Wg, Wu, Wd, Sg, Su, Sd,
                                                          WguT, WdT, SguT, SdT);

  logits_kernel<<<512, 256, 0, stream>>>(x, Wr, logits);
  assign_kernel<<<1, 1024, 0, stream>>>(logits, bias, list, ridx, rp, counts, offs);

  gemm_tn_kernel<0><<<dim3(32, 16, 9), 256, 0, stream>>>(
      Xb, He, Hs, WguT, SguT, WdT, SdT, He, Hs, De, Ds, list, counts, offs);
  gemm_tn_kernel<1><<<dim3(32, 8, 9), 256, 0, stream>>>(
      Xb, He, Hs, WguT, SguT, WdT, SdT, He, Hs, De, Ds, list, counts, offs);

  combine_kernel<<<2048, 256, 0, stream>>>(Ds, De, ridx, rp, out);
}